// Round 6
// baseline (114.314 us; speedup 1.0000x reference)
//
#include <hip/hip_runtime.h>
#include <hip/hip_fp16.h>

#define VOL    256
#define NPROJ  256
#define NDET   384
#define NS     256
#define PROW   129                 // padded-row stride in DWORDS (258 halves)
#define PDWN   (258 * PROW)        // 33282 dwords = 133,128 B in LDS
#define TPB    768                 // 12 waves; grid 256 = 1 block/CU, batch-pure

// Single kernel: stage zero-padded fp16 image into LDS straight from the fp32
// source, then each thread integrates its own ray over its exact in-volume
// sample interval (guard-free inner loop).
__global__ __launch_bounds__(TPB) void fanproj_kernel(const float* __restrict__ xin,
                                                      float* __restrict__ out) {
    __shared__ uint sImg[PDWN];

    int tid = threadIdx.x;
    int ray = blockIdx.x * TPB + tid;                  // b*P*D + p*D + d
    int b   = blockIdx.x >> 7;                         // 128 blocks per batch

    // ---- stage: sImg[uy*PROW+q] = half2{ P(uy,2q), P(uy,2q+1) },
    //      P(uy,ux) = img[uy-1][ux-1] zero-padded ----
    const float* im = xin + (b << 16);
    for (int i = tid; i < PDWN; i += TPB) {
        int uy = i / PROW;
        int q  = i - uy * PROW;
        int r  = uy - 1;
        int c0 = 2 * q - 1;                            // cols c0, c0+1
        float v0 = 0.0f, v1 = 0.0f;
        if ((unsigned)r < 256u) {
            const float* rp = im + (r << 8);
            if ((unsigned)c0 < 256u)       v0 = rp[c0];
            if ((unsigned)(c0 + 1) < 256u) v1 = rp[c0 + 1];
        }
        __half2 h = __floats2half2_rn(v0, v1);
        sImg[i] = *reinterpret_cast<uint*>(&h);
    }

    // ---- per-ray geometry ----
    int d  = ray % NDET;
    int pb = ray / NDET;
    int p  = pb & (NPROJ - 1);

    const float dt = 1.4142135623730951f;              // diag / NS = sqrt(2)
    const float t0 = 219.68777079743137f;              // SID - diag/2 + 0.5*dt

    float theta = (float)p * (6.283185307179586f / (float)NPROJ);
    float st, ct;
    sincosf(theta, &st, &ct);

    float srcx = -400.0f * ct;
    float srcy = -400.0f * st;
    float off  = ((float)d - 191.5f) * 1.2f;
    float rx   = fmaf(800.0f, ct, -off * st);
    float ry   = fmaf(800.0f, st,  off * ct);
    float n2   = rx * rx + ry * ry;
    float rn   = rsqrtf(n2);
    rn = rn * (1.5f - 0.5f * n2 * rn * rn);            // one Newton step
    rx *= rn;
    ry *= rn;

    float bx = fmaf(t0, rx, srcx) + 127.5f;            // +(VOL-1)/2 folded in
    float by = fmaf(t0, ry, srcy) + 127.5f;
    float sx = dt * rx;
    float sy = dt * ry;

    // ---- conservative s-interval where x,y in [-1,256), then exact refine ----
    float sxs = (fabsf(sx) < 1e-12f) ? copysignf(1e-12f, sx) : sx;
    float sys = (fabsf(sy) < 1e-12f) ? copysignf(1e-12f, sy) : sy;
    float isx = 1.0f / sxs;
    float isy = 1.0f / sys;
    float ax = (-1.0f - bx) * isx, bxb = (256.0f - bx) * isx;
    float ay = (-1.0f - by) * isy, byb = (256.0f - by) * isy;
    float lo = fmaxf(fminf(ax, bxb), fminf(ay, byb));
    float hi = fminf(fmaxf(ax, bxb), fmaxf(ay, byb));
    lo = fminf(fmaxf(lo, -2.0f), 300.0f);              // safe int-cast range
    hi = fminf(fmaxf(hi, -2.0f), 300.0f);
    int slo = max(0, (int)lo - 2);
    int shi = min(NS - 1, (int)hi + 2);

    // exact predicate: floor(x) in [-1,255] && floor(y) in [-1,255]
    #define INB(S) ({ float _x = fmaf((float)(S), sx, bx);                  \
                      float _y = fmaf((float)(S), sy, by);                  \
                      (_x >= -1.0f) && (_x < 256.0f) &&                     \
                      (_y >= -1.0f) && (_y < 256.0f); })
    while (slo <= shi && !INB(slo)) ++slo;
    while (shi >= slo && !INB(shi)) --shi;
    #undef INB

    __syncthreads();                                   // LDS image ready

    // ---- guard-free integration over [slo, shi] ----
    float acc = 0.0f;
    float sf  = (float)slo;
    for (int s = slo; s <= shi; ++s) {
        float x = fmaf(sf, sx, bx);
        float y = fmaf(sf, sy, by);
        sf += 1.0f;
        float xf = floorf(x);
        float yf = floorf(y);
        float wx = x - xf;
        float wy = y - yf;
        int ux = (int)xf + 1;                          // in [0,256]
        int uy = (int)yf + 1;                          // in [0,256]
        int base = uy * PROW + (ux >> 1);
        uint d0 = sImg[base];                          // row uy   (pair merge)
        uint d2 = sImg[base + PROW];                   // row uy+1
        uint d1 = d0, d3 = d2;
        if (ux & 1) {                                  // odd: pair straddles
            d1 = sImg[base + 1];
            d3 = sImg[base + PROW + 1];
        }
        unsigned sh = (unsigned)(ux & 1) << 4;
        uint tw = __builtin_amdgcn_alignbit(d1, d0, sh);   // {v(y0,x0),v(y0,x0+1)}
        uint bw = __builtin_amdgcn_alignbit(d3, d2, sh);   // {v(y1,x0),v(y1,x0+1)}
        __half2 ht = *reinterpret_cast<__half2*>(&tw);
        __half2 hb = *reinterpret_cast<__half2*>(&bw);
        float2 rt = __half22float2(ht);
        float2 rb = __half22float2(hb);
        float top = fmaf(wx, rt.y - rt.x, rt.x);
        float bot = fmaf(wx, rb.y - rb.x, rb.x);
        acc = fmaf(wy, bot - top, top) + acc;
    }
    out[ray] = acc * dt;
}

extern "C" void kernel_launch(void* const* d_in, const int* in_sizes, int n_in,
                              void* d_out, int out_size, void* d_ws, size_t ws_size,
                              hipStream_t stream) {
    const float* x = (const float*)d_in[0];
    float* out     = (float*)d_out;
    // 256 blocks x 768 threads = 196608 rays exactly; one dispatch total
    fanproj_kernel<<<256, TPB, 0, stream>>>(x, out);
}

// Round 8
// 89.674 us; speedup vs baseline: 1.2748x; 1.2748x over previous
//
#include <hip/hip_runtime.h>
#include <hip/hip_fp16.h>

#define VOL    256
#define NPROJ  256
#define NDET   384
#define NS     256
#define PROW   129                 // padded-row stride in DWORDS (258 halves)
#define PDWN   (258 * PROW)        // 33282 dwords of real texture
#define PDW    33284               // rounded up to uint4 multiple
#define PV4    (PDW / 4)           // 8321 uint4 = 133,136 B LDS
#define NBATCH 2
#define TPB    768                 // 12 waves; grid 256 = 1 block/CU, batch-pure

typedef _Float16 hvec2 __attribute__((ext_vector_type(2)));

#if defined(__has_builtin)
#if __has_builtin(__builtin_amdgcn_fdot2)
#define HAS_FDOT2 1
#endif
#endif

// Zero-padded fp16 image texture in ws: dword[uy*PROW+q] = half2{P(uy,2q),P(uy,2q+1)},
// P(uy,ux) = img[uy-1][ux-1], zero outside. (Identical to round-5's verified builder.)
__global__ void pad_build_kernel(const float* __restrict__ src, uint* __restrict__ dst) {
    int idx = blockIdx.x * blockDim.x + threadIdx.x;   // over NBATCH*PDW
    if (idx >= NBATCH * PDW) return;
    int b = idx / PDW;
    int d = idx - b * PDW;
    uint val = 0u;
    if (d < PDWN) {
        int uy = d / PROW;
        int q  = d - uy * PROW;
        int r  = uy - 1;
        int c0 = 2 * q - 1;
        const float* im = src + (b << 16);
        float v0 = 0.0f, v1 = 0.0f;
        if ((unsigned)r < 256u) {
            const float* rp = im + (r << 8);
            if ((unsigned)c0 < 256u)       v0 = rp[c0];
            if ((unsigned)(c0 + 1) < 256u) v1 = rp[c0 + 1];
        }
        __half2 h = __floats2half2_rn(v0, v1);
        val = *reinterpret_cast<uint*>(&h);
    }
    dst[idx] = val;
}

__global__ __launch_bounds__(TPB) void fanproj_kernel(const uint4* __restrict__ G,
                                                      float* __restrict__ out) {
    __shared__ uint4 s4[PV4];                          // 133,136 B -> 1 block/CU
    const uint* sImg = reinterpret_cast<const uint*>(s4);

    int tid = threadIdx.x;
    int ray = blockIdx.x * TPB + tid;                  // b*P*D + p*D + d
    int b   = blockIdx.x >> 7;                         // 128 blocks per batch

    // contiguous uint4 stage of this batch's texture (the fast R5 path)
    {
        const uint4* gb = G + (size_t)b * PV4;
        for (int i = tid; i < PV4; i += TPB) s4[i] = gb[i];
    }

    int d  = ray % NDET;
    int pb = ray / NDET;
    int p  = pb & (NPROJ - 1);

    const float dt = 1.4142135623730951f;              // diag / NS = sqrt(2)
    const float t0 = 219.68777079743137f;              // SID - diag/2 + 0.5*dt

    float theta = (float)p * (6.283185307179586f / (float)NPROJ);
    float st, ct;
    __sincosf(theta, &st, &ct);

    float srcx = -400.0f * ct;
    float srcy = -400.0f * st;
    float off  = ((float)d - 191.5f) * 1.2f;
    float rx   = fmaf(800.0f, ct, -off * st);
    float ry   = fmaf(800.0f, st,  off * ct);
    float n2   = rx * rx + ry * ry;
    float rn   = rsqrtf(n2);
    rn = rn * (1.5f - 0.5f * n2 * rn * rn);            // one Newton step
    rx *= rn;
    ry *= rn;

    // ux-space coordinates: X(s) = bxu + s*sx, valid when X,Y in [0, 257)
    float bxu = fmaf(t0, rx, srcx) + 128.5f;           // (VOL-1)/2 + 1 folded in
    float byu = fmaf(t0, ry, srcy) + 128.5f;
    float sx  = dt * rx;
    float sy  = dt * ry;

    // analytic guard-free interval, shrunk by EPS samples (boundary samples
    // carry weight <= ~3e-3 against the zero border -> negligible, and the
    // shrink guarantees every evaluated footprint is inside the padded texture)
    const float EPS = 2e-3f;
    float sxs = (fabsf(sx) < 1e-9f) ? copysignf(1e-9f, sx) : sx;
    float sys = (fabsf(sy) < 1e-9f) ? copysignf(1e-9f, sy) : sy;
    float isx = 1.0f / sxs;
    float isy = 1.0f / sys;
    float ax0 = (0.0f   - bxu) * isx, ax1 = (257.0f - bxu) * isx;
    float ay0 = (0.0f   - byu) * isy, ay1 = (257.0f - byu) * isy;
    float lo  = fmaxf(fminf(ax0, ax1), fminf(ay0, ay1)) + EPS;
    float hi  = fminf(fmaxf(ax0, ax1), fmaxf(ay0, ay1)) - EPS;
    lo = fminf(fmaxf(lo, -1.0f), 300.0f);              // safe cast range
    hi = fminf(fmaxf(hi, -1.0f), 300.0f);
    int slo = max(0,      (int)ceilf(lo));
    int shi = min(NS - 1, (int)floorf(hi));

    __syncthreads();                                   // LDS image ready

    float acc = 0.0f;
    float sf  = (float)slo;
    for (int s = slo; s <= shi; ++s) {
        float X = fmaf(sf, sx, bxu);
        float Y = fmaf(sf, sy, byu);
        sf += 1.0f;
        float Xf = floorf(X);
        float Yf = floorf(Y);
        float wx = X - Xf;
        float wy = Y - Yf;
        int ux = (int)Xf;                              // in [0,256]
        int uy = (int)Yf;                              // in [0,256]
        int base = uy * PROW + (ux >> 1);
        uint d0 = sImg[base];                          // merge -> ds_read2_b32 0,1
        uint d1 = sImg[base + 1];
        uint d2 = sImg[base + PROW];                   // merge -> ds_read2_b32 129,130
        uint d3 = sImg[base + PROW + 1];
        unsigned sh = (unsigned)(ux & 1) << 4;
        uint tw = __builtin_amdgcn_alignbit(d1, d0, sh);   // {v(y0,x0), v(y0,x0+1)}
        uint bw = __builtin_amdgcn_alignbit(d3, d2, sh);   // {v(y1,x0), v(y1,x0+1)}
#ifdef HAS_FDOT2
        hvec2 hx = __builtin_bit_cast(hvec2, __builtin_amdgcn_cvt_pkrtz(1.0f - wx, wx));
        hvec2 tv = __builtin_bit_cast(hvec2, tw);
        hvec2 bv = __builtin_bit_cast(hvec2, bw);
        float top = __builtin_amdgcn_fdot2(tv, hx, 0.0f, false);
        float bot = __builtin_amdgcn_fdot2(bv, hx, 0.0f, false);
        acc = fmaf(wy, bot - top, acc + top);
#else
        __half2 ht = *reinterpret_cast<__half2*>(&tw);
        __half2 hb = *reinterpret_cast<__half2*>(&bw);
        float2 rt = __half22float2(ht);
        float2 rb = __half22float2(hb);
        float top = fmaf(wx, rt.y - rt.x, rt.x);
        float bot = fmaf(wx, rb.y - rb.x, rb.x);
        acc = fmaf(wy, bot - top, acc + top);
#endif
    }
    out[ray] = acc * dt;
}

extern "C" void kernel_launch(void* const* d_in, const int* in_sizes, int n_in,
                              void* d_out, int out_size, void* d_ws, size_t ws_size,
                              hipStream_t stream) {
    const float* x = (const float*)d_in[0];
    float* out     = (float*)d_out;
    uint* hpad     = (uint*)d_ws;                      // NBATCH*PDW*4 = 266 KB

    int ndw = NBATCH * PDW;                            // 66568
    pad_build_kernel<<<(ndw + 255) / 256, 256, 0, stream>>>(x, hpad);

    // 256 blocks x 768 threads = 196608 rays exactly; blocks batch-pure
    fanproj_kernel<<<256, TPB, 0, stream>>>((const uint4*)hpad, out);
}